// Round 10
// baseline (256.919 us; speedup 1.0000x reference)
//
#include <hip/hip_runtime.h>

// Problem constants (match reference)
constexpr int BB  = 8;
constexpr int NN  = 2048;
constexpr int IND = 128;
constexpr int HD  = 64;
constexpr float LN_EPS = 1e-5f;
constexpr float SLOPE  = 0.2f;

typedef _Float16 half8 __attribute__((ext_vector_type(8)));
typedef _Float16 half4 __attribute__((ext_vector_type(4)));
typedef float    f32x4 __attribute__((ext_vector_type(4)));

__device__ __forceinline__ float wave_sum(float v) {
    #pragma unroll
    for (int off = 32; off > 0; off >>= 1) v += __shfl_xor(v, off);
    return v;
}
__device__ __forceinline__ float wave_max(float v) {
    #pragma unroll
    for (int off = 32; off > 0; off >>= 1) v = fmaxf(v, __shfl_xor(v, off));
    return v;
}

// ---------------------------------------------------------------------------
// Kernel 0 (unchanged): build Wt[256 cols][192 k] fp16, k-major.
// ---------------------------------------------------------------------------
__global__ void k_prep(const float* __restrict__ X2H, const float* __restrict__ H2H,
                       _Float16* __restrict__ Wt)
{
    const int tot = 256 * 192;
    for (int idx = blockIdx.x * 256 + threadIdx.x; idx < tot; idx += gridDim.x * 256) {
        const int col = idx / 192, k = idx % 192;
        float v;
        if (col < 128)       v = (k < 128) ? X2H[(size_t)k * 192 + col]
                                           : H2H[(size_t)(k - 128) * 192 + col];
        else if (col < 192)  v = (k < 128) ? X2H[(size_t)k * 192 + col] : 0.f;
        else                 v = (k >= 128) ? H2H[(size_t)(k - 128) * 192 + (col - 64)] : 0.f;
        Wt[idx] = (_Float16)v;
    }
}

// ---------------------------------------------------------------------------
// Kernel 1 (unchanged): gates via fp16 MFMA, 16 rows x 4 waves.
// ---------------------------------------------------------------------------
__global__ __launch_bounds__(256, 4) void k_gates(
    const float* __restrict__ x, const float* __restrict__ h,
    const _Float16* __restrict__ Wt, const float* __restrict__ a,
    float* __restrict__ Wh_out, _Float16* __restrict__ Whh2,
    float* __restrict__ Wh1, float* __restrict__ Wh2)
{
    __shared__ float gbuf[16][260];

    const int tid = threadIdx.x, lane = tid & 63, w = tid >> 6;
    const int m = lane & 15, q = lane >> 4;
    const int row0 = blockIdx.x * 16;

    f32x4 acc[4];
    #pragma unroll
    for (int ct = 0; ct < 4; ++ct) acc[ct] = (f32x4){0.f, 0.f, 0.f, 0.f};

    #pragma unroll
    for (int kc = 0; kc < 6; ++kc) {
        half8 a8;
        if (kc < 4) {
            const float* xp = x + (size_t)(row0 + m) * IND + kc * 32 + q * 8;
            const f32x4 v0 = *(const f32x4*)xp;
            const f32x4 v1 = *(const f32x4*)(xp + 4);
            #pragma unroll
            for (int j = 0; j < 4; ++j) { a8[j] = (_Float16)v0[j]; a8[4 + j] = (_Float16)v1[j]; }
        } else {
            const float* hp_ = h + (size_t)(row0 + m) * HD + (kc - 4) * 32 + q * 8;
            const f32x4 v0 = *(const f32x4*)hp_;
            const f32x4 v1 = *(const f32x4*)(hp_ + 4);
            #pragma unroll
            for (int j = 0; j < 4; ++j) { a8[j] = (_Float16)v0[j]; a8[4 + j] = (_Float16)v1[j]; }
        }
        #pragma unroll
        for (int ct = 0; ct < 4; ++ct) {
            const half8 b8 = *(const half8*)(Wt + ((size_t)(w * 64 + ct * 16 + m) * 192 + kc * 32 + q * 8));
            acc[ct] = __builtin_amdgcn_mfma_f32_16x16x32_f16(a8, b8, acc[ct], 0, 0, 0);
        }
    }

    #pragma unroll
    for (int ct = 0; ct < 4; ++ct)
        #pragma unroll
        for (int r2 = 0; r2 < 4; ++r2)
            gbuf[q * 4 + r2][w * 64 + ct * 16 + m] = acc[ct][r2];
    __syncthreads();

    const float a0 = a[lane], a1 = a[64 + lane];
    half4 p4;
    const int grow0 = row0 + w * 4;
    #pragma unroll
    for (int r = 0; r < 4; ++r) {
        const int row = w * 4 + r;
        const int grow = row0 + row;
        const float g0 = gbuf[row][lane];
        const float g1 = gbuf[row][64 + lane];
        const float g2 = gbuf[row][128 + lane];
        const float g3 = gbuf[row][192 + lane];
        const float rg = 1.f / (1.f + __expf(-g0));
        const float ig = 1.f / (1.f + __expf(-g1));
        const float irh = g2 + rg * g3;
        const float mu = wave_sum(irh) * (1.f / 64.f);
        const float dv = irh - mu;
        const float var = wave_sum(dv * dv) * (1.f / 64.f);
        const float ng = tanhf(dv * rsqrtf(var + LN_EPS));
        const float hr = h[(size_t)grow * HD + lane];
        const float wh = ng + ig * (hr - ng);
        Wh_out[(size_t)grow * HD + lane] = wh;
        p4[r] = (_Float16)wh;
        const float d1 = wave_sum(wh * a0);
        const float d2 = wave_sum(wh * a1);
        if (lane == 0) { Wh1[grow] = d1; Wh2[grow] = d2; }
    }
    *(half4*)(Whh2 + ((size_t)(grow0 >> 3) * 64 + lane) * 8 + (w & 1) * 4) = p4;
}

// ---------------------------------------------------------------------------
// Kernel 2: aux — batch max + separable softmax factors.
//   u  = exp(t0 - c), u' = exp(0.2 t0 - c)   (t0 = Wh1+M, c = lrelu(t0))
//   v  = exp(Wh2 - M), v' = exp(0.2(Wh2-M))  (all <= 1)
// grid 64: block (b, part) handles rows part*256..+255 of batch b.
// ---------------------------------------------------------------------------
__global__ __launch_bounds__(256) void k_aux(
    const float* __restrict__ Wh1, const float* __restrict__ Wh2,
    float* __restrict__ u, float* __restrict__ up,
    _Float16* __restrict__ v16, _Float16* __restrict__ v16p)
{
    __shared__ float red[4];
    const int tid = threadIdx.x, lane = tid & 63, w = tid >> 6;
    const int b = blockIdx.x >> 3, part = blockIdx.x & 7;

    float mx = -3e38f;
    #pragma unroll
    for (int k = 0; k < 8; ++k) mx = fmaxf(mx, Wh2[b * NN + k * 256 + tid]);
    mx = wave_max(mx);
    if (lane == 0) red[w] = mx;
    __syncthreads();
    const float M = fmaxf(fmaxf(red[0], red[1]), fmaxf(red[2], red[3]));

    const int grow = b * NN + part * 256 + tid;
    const float t0 = Wh1[grow] + M;
    const float c  = (t0 > 0.f) ? t0 : SLOPE * t0;
    u[grow]  = __expf(t0 - c);
    up[grow] = __expf(SLOPE * t0 - c);
    const float w2 = Wh2[grow] - M;
    v16[grow]  = (_Float16)__expf(w2);
    v16p[grow] = (_Float16)__expf(SLOPE * w2);
}

// ---------------------------------------------------------------------------
// Kernel 3: scores -> bitmasks.  PURE LINEAR STREAM, block-uniform row.
// Thread (row, slot=tid) covers cols [8*slot, 8*slot+8):
//   bit j of m1 = adj && (Wh1_row + Wh2_col > 0);  m0 = adj && !s.
// Mb[row][slot] = m1 | (m0<<8).  No exp, no LDS, no barriers.
// ---------------------------------------------------------------------------
__global__ __launch_bounds__(256, 8) void k_score(
    const int* __restrict__ adj,
    const float* __restrict__ Wh1, const float* __restrict__ Wh2,
    unsigned short* __restrict__ Mb)
{
    const int tid = threadIdx.x;
    const int4* __restrict__ adj4 = (const int4*)adj;

    #pragma unroll
    for (int s = 0; s < 4; ++s) {
        const int row = s * 4096 + blockIdx.x;        // 0..16383
        const int b   = row >> 11;
        const float negw1 = -Wh1[row];                // block-uniform scalar

        const int4 a0 = adj4[(size_t)row * 512 + tid * 2];
        const int4 a1 = adj4[(size_t)row * 512 + tid * 2 + 1];
        const f32x4 w0 = ((const f32x4*)(Wh2 + (size_t)b * NN))[tid * 2];
        const f32x4 w1 = ((const f32x4*)(Wh2 + (size_t)b * NN))[tid * 2 + 1];

        unsigned m1 = 0, m0 = 0;
        const int av[8] = {a0.x, a0.y, a0.z, a0.w, a1.x, a1.y, a1.z, a1.w};
        #pragma unroll
        for (int j = 0; j < 8; ++j) {
            const float wj = (j < 4) ? w0[j] : w1[j - 4];
            const bool a = (av[j] != 0);
            const bool ss = (wj > negw1);
            m1 |= (unsigned)(a && ss) << j;
            m0 |= (unsigned)(a && !ss) << j;
        }
        Mb[(size_t)row * 256 + tid] = (unsigned short)(m1 | (m0 << 8));
    }
}

// ---------------------------------------------------------------------------
// Kernel 4: h' = (P @ Wh) / rowsum(P) from bitmasks.  Block = 16 rows x 4
// waves, K-split 512/wave.  A-fragment built in-regs:
//   Ac[j] = m1 ? uh*v_j : m0 ? u'h*v'_j : 0     (disjoint branches)
// B = k-packed Whh2 (4 col-chunks) + ones (row-sum chain): 5 MFMA / k-step.
// Epilogue: 4-way K-combine + transpose via LDS, coalesced f32x4 stores.
// ---------------------------------------------------------------------------
__global__ __launch_bounds__(256, 4) void k_pv(
    const unsigned short* __restrict__ Mb,
    const _Float16* __restrict__ Whh2,   // [B][256][64][8]
    const _Float16* __restrict__ v16, const _Float16* __restrict__ v16p,
    const float* __restrict__ u, const float* __restrict__ up,
    float* __restrict__ hp)
{
    __shared__ float accb[4][64][20];
    __shared__ float ssumw[4][16];

    const int tid = threadIdx.x, lane = tid & 63, w = tid >> 6;
    const int m = lane & 15, q = lane >> 4;
    const int b  = blockIdx.x >> 7;
    const int i0 = (blockIdx.x & 127) * 16;

    const int grow_m = b * NN + i0 + m;
    const _Float16 uh  = (_Float16)u[grow_m];
    const _Float16 uph = (_Float16)up[grow_m];

    const unsigned short* __restrict__ mrow = Mb + (size_t)grow_m * 256 + w * 64;
    const half8* __restrict__ Wp  = (const half8*)Whh2 + (size_t)b * 16384;
    const half8* __restrict__ v8  = (const half8*)v16  + b * 256;
    const half8* __restrict__ v8p = (const half8*)v16p + b * 256;

    half8 ones;
    #pragma unroll
    for (int j = 0; j < 8; ++j) ones[j] = (_Float16)1.f;

    f32x4 acc[4];
    #pragma unroll
    for (int cc = 0; cc < 4; ++cc) acc[cc] = (f32x4){0.f, 0.f, 0.f, 0.f};
    f32x4 accS = (f32x4){0.f, 0.f, 0.f, 0.f};

    #pragma unroll
    for (int k8 = 0; k8 < 16; ++k8) {
        const int slot  = k8 * 4 + q;
        const int kpack = w * 64 + slot;
        const unsigned mb = mrow[slot];
        const unsigned m1b = mb & 0xFFu, m0b = mb >> 8;

        const half8 vj  = v8[kpack];     // quad-broadcast
        const half8 vjp = v8p[kpack];

        half8 Ac;
        #pragma unroll
        for (int j = 0; j < 8; ++j) {
            const _Float16 pos = uh * vj[j];
            const _Float16 neg = uph * vjp[j];
            Ac[j] = (m1b >> j & 1u) ? pos : ((m0b >> j & 1u) ? neg : (_Float16)0.f);
        }

        accS = __builtin_amdgcn_mfma_f32_16x16x32_f16(Ac, ones, accS, 0, 0, 0);
        #pragma unroll
        for (int cc = 0; cc < 4; ++cc) {
            const half8 b8 = Wp[(size_t)kpack * 64 + cc * 16 + m];
            acc[cc] = __builtin_amdgcn_mfma_f32_16x16x32_f16(Ac, b8, acc[cc], 0, 0, 0);
        }
    }

    if (m == 0) {
        #pragma unroll
        for (int r2 = 0; r2 < 4; ++r2) ssumw[w][q * 4 + r2] = accS[r2];
    }
    #pragma unroll
    for (int cc = 0; cc < 4; ++cc)
        *(f32x4*)&accb[w][lane][cc * 4] = acc[cc];
    __syncthreads();

    const int row = tid >> 4, c4 = tid & 15;
    const float S = ssumw[0][row] + ssumw[1][row] + ssumw[2][row] + ssumw[3][row];
    const int rq = row >> 2, r2 = row & 3;
    f32x4 tot;
    #pragma unroll
    for (int j = 0; j < 4; ++j) {
        const int col = c4 * 4 + j;
        const int cc = col >> 4, mm = col & 15;
        const int ln = rq * 16 + mm;
        float v = 0.f;
        #pragma unroll
        for (int wp = 0; wp < 4; ++wp) v += accb[wp][ln][cc * 4 + r2];
        tot[j] = v / S;
    }
    *(f32x4*)(hp + ((size_t)(b * NN + i0 + row)) * HD + c4 * 4) = tot;
}

// ---------------------------------------------------------------------------
extern "C" void kernel_launch(void* const* d_in, const int* in_sizes, int n_in,
                              void* d_out, int out_size, void* d_ws, size_t ws_size,
                              hipStream_t stream) {
    const int*   adj = (const int*)d_in[0];
    const float* x   = (const float*)d_in[1];
    const float* h   = (const float*)d_in[2];
    const float* X2H = (const float*)d_in[3];
    const float* H2H = (const float*)d_in[4];
    const float* a   = (const float*)d_in[5];

    float* out = (float*)d_out;
    float* hp  = out;                              // h_prime [8][2048][64]
    float* Wh  = out + (size_t)BB * NN * HD;       // Wh      [8][2048][64]

    // workspace (~10.4 MB)
    float*    Wh1  = (float*)d_ws;                      // [16384]
    float*    Wh2  = Wh1 + BB * NN;                     // [16384]
    float*    u    = Wh2 + BB * NN;                     // [16384]
    float*    up   = u + BB * NN;                       // [16384]
    _Float16* v16  = (_Float16*)(up + BB * NN);         // [16384]
    _Float16* v16p = v16 + BB * NN;                     // [16384]
    _Float16* Whh2 = v16p + BB * NN;                    // [B][256][64][8] = 2 MB
    _Float16* Wt   = Whh2 + (size_t)BB * NN * HD;       // [256][192]
    unsigned short* Mb = (unsigned short*)(Wt + 256 * 192);  // [16384][256] = 8 MB

    k_prep<<<dim3(64), dim3(256), 0, stream>>>(X2H, H2H, Wt);
    k_gates<<<dim3((BB * NN) / 16), dim3(256), 0, stream>>>(
        x, h, Wt, a, Wh, Whh2, Wh1, Wh2);
    k_aux<<<dim3(64), dim3(256), 0, stream>>>(Wh1, Wh2, u, up, v16, v16p);
    k_score<<<dim3(4096), dim3(256), 0, stream>>>(adj, Wh1, Wh2, Mb);
    k_pv<<<dim3(BB * (NN / 16)), dim3(256), 0, stream>>>(
        Mb, Whh2, v16, v16p, u, up, hp);
}

// Round 12
// 248.326 us; speedup vs baseline: 1.0346x; 1.0346x over previous
//
#include <hip/hip_runtime.h>

// Problem constants (match reference)
constexpr int BB  = 8;
constexpr int NN  = 2048;
constexpr int IND = 128;
constexpr int HD  = 64;
constexpr float LN_EPS = 1e-5f;
constexpr float SLOPE  = 0.2f;

typedef _Float16 half8 __attribute__((ext_vector_type(8)));
typedef _Float16 half4 __attribute__((ext_vector_type(4)));
typedef float    f32x4 __attribute__((ext_vector_type(4)));

__device__ __forceinline__ float wave_sum(float v) {
    #pragma unroll
    for (int off = 32; off > 0; off >>= 1) v += __shfl_xor(v, off);
    return v;
}
__device__ __forceinline__ float wave_max(float v) {
    #pragma unroll
    for (int off = 32; off > 0; off >>= 1) v = fmaxf(v, __shfl_xor(v, off));
    return v;
}

// ---------------------------------------------------------------------------
// Kernel 0 (unchanged): build Wt[256 cols][192 k] fp16, k-major.
// ---------------------------------------------------------------------------
__global__ void k_prep(const float* __restrict__ X2H, const float* __restrict__ H2H,
                       _Float16* __restrict__ Wt)
{
    const int tot = 256 * 192;
    for (int idx = blockIdx.x * 256 + threadIdx.x; idx < tot; idx += gridDim.x * 256) {
        const int col = idx / 192, k = idx % 192;
        float v;
        if (col < 128)       v = (k < 128) ? X2H[(size_t)k * 192 + col]
                                           : H2H[(size_t)(k - 128) * 192 + col];
        else if (col < 192)  v = (k < 128) ? X2H[(size_t)k * 192 + col] : 0.f;
        else                 v = (k >= 128) ? H2H[(size_t)(k - 128) * 192 + (col - 64)] : 0.f;
        Wt[idx] = (_Float16)v;
    }
}

// ---------------------------------------------------------------------------
// Kernel 1 (unchanged): gates via fp16 MFMA, 16 rows x 4 waves.
// ---------------------------------------------------------------------------
__global__ __launch_bounds__(256, 4) void k_gates(
    const float* __restrict__ x, const float* __restrict__ h,
    const _Float16* __restrict__ Wt, const float* __restrict__ a,
    float* __restrict__ Wh_out, _Float16* __restrict__ Whh2,
    float* __restrict__ Wh1, float* __restrict__ Wh2)
{
    __shared__ float gbuf[16][260];

    const int tid = threadIdx.x, lane = tid & 63, w = tid >> 6;
    const int m = lane & 15, q = lane >> 4;
    const int row0 = blockIdx.x * 16;

    f32x4 acc[4];
    #pragma unroll
    for (int ct = 0; ct < 4; ++ct) acc[ct] = (f32x4){0.f, 0.f, 0.f, 0.f};

    #pragma unroll
    for (int kc = 0; kc < 6; ++kc) {
        half8 a8;
        if (kc < 4) {
            const float* xp = x + (size_t)(row0 + m) * IND + kc * 32 + q * 8;
            const f32x4 v0 = *(const f32x4*)xp;
            const f32x4 v1 = *(const f32x4*)(xp + 4);
            #pragma unroll
            for (int j = 0; j < 4; ++j) { a8[j] = (_Float16)v0[j]; a8[4 + j] = (_Float16)v1[j]; }
        } else {
            const float* hp_ = h + (size_t)(row0 + m) * HD + (kc - 4) * 32 + q * 8;
            const f32x4 v0 = *(const f32x4*)hp_;
            const f32x4 v1 = *(const f32x4*)(hp_ + 4);
            #pragma unroll
            for (int j = 0; j < 4; ++j) { a8[j] = (_Float16)v0[j]; a8[4 + j] = (_Float16)v1[j]; }
        }
        #pragma unroll
        for (int ct = 0; ct < 4; ++ct) {
            const half8 b8 = *(const half8*)(Wt + ((size_t)(w * 64 + ct * 16 + m) * 192 + kc * 32 + q * 8));
            acc[ct] = __builtin_amdgcn_mfma_f32_16x16x32_f16(a8, b8, acc[ct], 0, 0, 0);
        }
    }

    #pragma unroll
    for (int ct = 0; ct < 4; ++ct)
        #pragma unroll
        for (int r2 = 0; r2 < 4; ++r2)
            gbuf[q * 4 + r2][w * 64 + ct * 16 + m] = acc[ct][r2];
    __syncthreads();

    const float a0 = a[lane], a1 = a[64 + lane];
    half4 p4;
    const int grow0 = row0 + w * 4;
    #pragma unroll
    for (int r = 0; r < 4; ++r) {
        const int row = w * 4 + r;
        const int grow = row0 + row;
        const float g0 = gbuf[row][lane];
        const float g1 = gbuf[row][64 + lane];
        const float g2 = gbuf[row][128 + lane];
        const float g3 = gbuf[row][192 + lane];
        const float rg = 1.f / (1.f + __expf(-g0));
        const float ig = 1.f / (1.f + __expf(-g1));
        const float irh = g2 + rg * g3;
        const float mu = wave_sum(irh) * (1.f / 64.f);
        const float dv = irh - mu;
        const float var = wave_sum(dv * dv) * (1.f / 64.f);
        const float ng = tanhf(dv * rsqrtf(var + LN_EPS));
        const float hr = h[(size_t)grow * HD + lane];
        const float wh = ng + ig * (hr - ng);
        Wh_out[(size_t)grow * HD + lane] = wh;
        p4[r] = (_Float16)wh;
        const float d1 = wave_sum(wh * a0);
        const float d2 = wave_sum(wh * a1);
        if (lane == 0) { Wh1[grow] = d1; Wh2[grow] = d2; }
    }
    *(half4*)(Whh2 + ((size_t)(grow0 >> 3) * 64 + lane) * 8 + (w & 1) * 4) = p4;
}

// ---------------------------------------------------------------------------
// Kernel 2: aux — batch max + separable softmax factors (exact algebra):
//   t0 = Wh1+M, c = lrelu(t0);  u = exp(t0-c), u' = exp(0.2*t0-c)
//   v = exp(Wh2-M), v' = exp(0.2*(Wh2-M))    (all <= 1)
//   score>0:  P = u*v ;  score<=0: P = u'*v'
// ---------------------------------------------------------------------------
__global__ __launch_bounds__(256) void k_aux(
    const float* __restrict__ Wh1, const float* __restrict__ Wh2,
    float* __restrict__ u, float* __restrict__ up,
    _Float16* __restrict__ v16, _Float16* __restrict__ v16p)
{
    __shared__ float red[4];
    const int tid = threadIdx.x, lane = tid & 63, w = tid >> 6;
    const int b = blockIdx.x >> 3, part = blockIdx.x & 7;

    float mx = -3e38f;
    #pragma unroll
    for (int k = 0; k < 8; ++k) mx = fmaxf(mx, Wh2[b * NN + k * 256 + tid]);
    mx = wave_max(mx);
    if (lane == 0) red[w] = mx;
    __syncthreads();
    const float M = fmaxf(fmaxf(red[0], red[1]), fmaxf(red[2], red[3]));

    const int grow = b * NN + part * 256 + tid;
    const float t0 = Wh1[grow] + M;
    const float c  = (t0 > 0.f) ? t0 : SLOPE * t0;
    u[grow]  = __expf(t0 - c);
    up[grow] = __expf(SLOPE * t0 - c);
    const float w2 = Wh2[grow] - M;
    v16[grow]  = (_Float16)__expf(w2);
    v16p[grow] = (_Float16)__expf(SLOPE * w2);
}

// ---------------------------------------------------------------------------
// Kernel 3: fused attention.  Block = 512 threads (8 waves) x 16 query rows;
// wave w owns cols [w*256, w*256+256) end-to-end.
//  Phase A: 16 coalesced adj int4 loads (all in flight) -> 2-bit class per
//    element (adj & sign(Wh1+Wh2)), packed 4 rows/u32 -> 1 KB wave-private
//    LDS (no exp, no fp16 cvt in the stream).
//  Phase B: A-fragment rebuilt in-regs: Ac = cls1 ? u*v : cls0 ? u'*v' : 0;
//    4 col MFMAs + ones-chain row sums.  8-way combine via LDS.
// Mask stride 65 words => <=2-way banks (free).  No A->B barrier (wave-
// private LDS).  16 waves/CU.
// ---------------------------------------------------------------------------
constexpr int MST = 65;   // mask row-group stride (words)

__global__ __launch_bounds__(512, 4) void k_attn(
    const int* __restrict__ adj,
    const _Float16* __restrict__ Whh2,   // [B][256][64][8]
    const float* __restrict__ Wh1, const float* __restrict__ Wh2,
    const float* __restrict__ u, const float* __restrict__ up,
    const _Float16* __restrict__ v16, const _Float16* __restrict__ v16p,
    float* __restrict__ hp)
{
    __shared__ unsigned mk_all[8][4 * MST];   // 8.3 KB
    __shared__ float accb[8][64][17];         // 34.8 KB
    __shared__ float ssumw[8][16];

    const int tid  = threadIdx.x;
    const int lane = tid & 63;
    const int w    = tid >> 6;
    const int b    = blockIdx.x >> 7;
    const int i0   = (blockIdx.x & 127) * 16;
    const int m    = lane & 15;
    const int q    = lane >> 4;

    unsigned* __restrict__ mk = mk_all[w];

    // all 16 adj row-loads issued up front (coalesced: lane = 4 cols)
    const int* __restrict__ abase = adj + ((size_t)b * NN + i0) * NN + w * 256 + 4 * lane;
    int4 av[16];
    #pragma unroll
    for (int r = 0; r < 16; ++r) av[r] = *(const int4*)(abase + (size_t)r * NN);

    // this wave's 4 Wh2 cols (for the sign test)
    const f32x4 w2v = ((const f32x4*)(Wh2 + (size_t)b * NN))[w * 64 + lane];

    float negw1[16];
    #pragma unroll
    for (int r = 0; r < 16; ++r) negw1[r] = -Wh1[b * NN + i0 + r];

    // ---- Phase A: classify -> packed mask in wave-private LDS ----
    unsigned mword = 0;
    #pragma unroll
    for (int r = 0; r < 16; ++r) {
        const int ai[4] = {av[r].x, av[r].y, av[r].z, av[r].w};
        unsigned byte = 0;
        #pragma unroll
        for (int d = 0; d < 4; ++d) {
            const bool ad = (ai[d] != 0);
            const bool s  = (w2v[d] > negw1[r]);
            byte |= (unsigned)(ad && s)  << d;
            byte |= (unsigned)(ad && !s) << (4 + d);
        }
        mword |= byte << (8 * (r & 3));
        if ((r & 3) == 3) { mk[(r >> 2) * MST + lane] = mword; mword = 0; }
    }

    // ---- Phase B: A-fragment from mask x factors; 5 MFMA chains ----
    const int grow_m = b * NN + i0 + m;
    const _Float16 uh  = (_Float16)u[grow_m];
    const _Float16 uph = (_Float16)up[grow_m];
    const half8* __restrict__ v8  = (const half8*)(v16  + (size_t)b * NN);
    const half8* __restrict__ v8p = (const half8*)(v16p + (size_t)b * NN);
    const half8* __restrict__ Wp  = (const half8*)Whh2 + (size_t)b * 16384;

    half8 ones;
    #pragma unroll
    for (int j = 0; j < 8; ++j) ones[j] = (_Float16)1.f;

    f32x4 acc[4];
    #pragma unroll
    for (int cc = 0; cc < 4; ++cc) acc[cc] = (f32x4){0.f, 0.f, 0.f, 0.f};
    f32x4 accS = (f32x4){0.f, 0.f, 0.f, 0.f};

    const int rg = m >> 2, sh = 8 * (m & 3);
    #pragma unroll
    for (int k8 = 0; k8 < 8; ++k8) {
        const int cb0 = k8 * 8 + q * 2;
        const unsigned b0 = (mk[rg * MST + cb0]     >> sh) & 0xFFu;
        const unsigned b1 = (mk[rg * MST + cb0 + 1] >> sh) & 0xFFu;

        const int kv = w * 32 + k8 * 4 + q;
        const half8 vj  = v8[kv];
        const half8 vjp = v8p[kv];

        half8 Ac;
        #pragma unroll
        for (int j = 0; j < 4; ++j) {
            Ac[j]     = (b0 >> j & 1u) ? uh * vj[j]
                      : ((b0 >> (4 + j) & 1u) ? uph * vjp[j] : (_Float16)0.f);
            Ac[4 + j] = (b1 >> j & 1u) ? uh * vj[4 + j]
                      : ((b1 >> (4 + j) & 1u) ? uph * vjp[4 + j] : (_Float16)0.f);
        }

        accS = __builtin_amdgcn_mfma_f32_16x16x32_f16(Ac, ones, accS, 0, 0, 0);
        #pragma unroll
        for (int cc = 0; cc < 4; ++cc) {
            const half8 b8 = Wp[(size_t)kv * 64 + cc * 16 + m];
            acc[cc] = __builtin_amdgcn_mfma_f32_16x16x32_f16(Ac, b8, acc[cc], 0, 0, 0);
        }
    }

    if (m == 0) {
        #pragma unroll
        for (int r2 = 0; r2 < 4; ++r2) ssumw[w][q * 4 + r2] = accS[r2];
    }
    #pragma unroll
    for (int cc = 0; cc < 4; ++cc)
        *(f32x4*)&accb[w][lane][cc * 4] = acc[cc];
    __syncthreads();

    // waves 0-3: combine 8 partials for col-chunk cc=w, divide, store
    if (w < 4) {
        f32x4 tot = (f32x4){0.f, 0.f, 0.f, 0.f};
        #pragma unroll
        for (int wp = 0; wp < 8; ++wp) {
            const f32x4 t4 = *(const f32x4*)&accb[wp][lane][w * 4];
            tot[0] += t4[0]; tot[1] += t4[1]; tot[2] += t4[2]; tot[3] += t4[3];
        }
        #pragma unroll
        for (int r2 = 0; r2 < 4; ++r2) {
            const int irow = q * 4 + r2;
            float S = 0.f;
            #pragma unroll
            for (int wp = 0; wp < 8; ++wp) S += ssumw[wp][irow];
            hp[((size_t)b * NN + i0 + irow) * HD + w * 16 + m] = tot[r2] / S;
        }
    }
}

// ---------------------------------------------------------------------------
extern "C" void kernel_launch(void* const* d_in, const int* in_sizes, int n_in,
                              void* d_out, int out_size, void* d_ws, size_t ws_size,
                              hipStream_t stream) {
    const int*   adj = (const int*)d_in[0];
    const float* x   = (const float*)d_in[1];
    const float* h   = (const float*)d_in[2];
    const float* X2H = (const float*)d_in[3];
    const float* H2H = (const float*)d_in[4];
    const float* a   = (const float*)d_in[5];

    float* out = (float*)d_out;
    float* hp  = out;                              // h_prime [8][2048][64]
    float* Wh  = out + (size_t)BB * NN * HD;       // Wh      [8][2048][64]

    // workspace (~2.6 MB)
    float*    Wh1  = (float*)d_ws;                      // [16384]
    float*    Wh2  = Wh1 + BB * NN;                     // [16384]
    float*    u    = Wh2 + BB * NN;                     // [16384]
    float*    up   = u + BB * NN;                       // [16384]
    _Float16* v16  = (_Float16*)(up + BB * NN);         // [16384]
    _Float16* v16p = v16 + BB * NN;                     // [16384]
    _Float16* Whh2 = v16p + BB * NN;                    // [B][256][64][8] = 2 MB
    _Float16* Wt   = Whh2 + (size_t)BB * NN * HD;       // [256][192]

    k_prep<<<dim3(64), dim3(256), 0, stream>>>(X2H, H2H, Wt);
    k_gates<<<dim3((BB * NN) / 16), dim3(256), 0, stream>>>(
        x, h, Wt, a, Wh, Whh2, Wh1, Wh2);
    k_aux<<<dim3(64), dim3(256), 0, stream>>>(Wh1, Wh2, u, up, v16, v16p);
    k_attn<<<dim3(BB * (NN / 16)), dim3(512), 0, stream>>>(
        adj, Whh2, Wh1, Wh2, u, up, v16, v16p, hp);
}